// Round 1
// baseline (272.673 us; speedup 1.0000x reference)
//
#include <hip/hip_runtime.h>

// MultiscaleLLN: out = x / (gauss13x13(lum(x)) / dens + eps), 4 pyramid levels.
// Gaussian (sigma=3) is exactly separable; dens is analytic (prefix sums of G1).
// Memory-bound: target = 1 read of x + 1 write of out (~267 MB).

#define NPIX   87040
#define EPSV   1e-3f
#define WSUM   0.9999f      // 0.2989 + 0.587 + 0.114
#define TW     64
#define TH     32
#define RAD    6
#define RW     (TW + 2*RAD) // 76
#define RH     (TH + 2*RAD) // 44

// 1D Gaussian taps G1[d+6] = exp(-d^2/18)/sqrt(18*pi), d = -6..6
__device__ __constant__ float G1[13] = {
    0.01799699f, 0.03315904f, 0.05467002f, 0.08065689f, 0.10648267f,
    0.12579441f, 0.13298076f, 0.12579441f, 0.10648267f, 0.08065689f,
    0.05467002f, 0.03315904f, 0.01799699f
};
// prefix sums PRE[i] = sum_{j<i} G1[j]
__device__ __constant__ float PRE[14] = {
    0.00000000f, 0.01799699f, 0.05115603f, 0.10582605f, 0.18648294f,
    0.29296561f, 0.41876002f, 0.55174078f, 0.67753519f, 0.78401786f,
    0.86467475f, 0.91934477f, 0.95250381f, 0.97050080f
};

__global__ __launch_bounds__(256)
void mslln_kernel(const float* __restrict__ x, float* __restrict__ out) {
    __shared__ float s_lum[RH][RW];   // luminance tile + halo, 44x76
    __shared__ float s_rc[RH][TW];    // row-convolved, 44x64

    const int bid = blockIdx.x;
    const int t   = threadIdx.x;

    // block -> (level, image, tile) decode; tiles are 64x32 outputs
    // L0: 256x256 -> 4x8=32 tiles * 128 imgs = 4096 blocks  [0,4096)
    // L1: 128x128 -> 2x4=8  tiles * 128      = 1024         [4096,5120)
    // L2:  64x64  -> 1x2=2  tiles * 128      =  256         [5120,5376)
    // L3:  32x32  -> 1      tile  * 128      =  128         [5376,5504)
    int img, tl, txlog, h, off;
    if (bid < 4096)      { img = bid >> 5;          tl = bid & 31;         txlog = 2; h = 256; off = 0;     }
    else if (bid < 5120) { int r = bid - 4096; img = r >> 3; tl = r & 7;   txlog = 1; h = 128; off = 65536; }
    else if (bid < 5376) { int r = bid - 5120; img = r >> 1; tl = r & 1;   txlog = 0; h = 64;  off = 81920; }
    else                 { img = bid - 5376;        tl = 0;                txlog = 0; h = 32;  off = 86016; }
    const int w   = h;
    const int tx0 = (tl & ((1 << txlog) - 1)) << 6;  // *64
    const int ty0 = (tl >> txlog) << 5;              // *32

    const float* __restrict__ xb = x   + (size_t)img * (NPIX * 3) + (size_t)off * 3;
    float*       __restrict__ ob = out + (size_t)img * (NPIX * 3) + (size_t)off * 3;

    // ---- Phase 1a: interior RGB -> registers, lum -> LDS ----
    float rr[8], rg[8], rb[8];
#pragma unroll
    for (int k = 0; k < 8; k++) {
        int p  = t + k * 256;
        int lx = p & 63, ly = p >> 6;
        int gy = ty0 + ly, gx = tx0 + lx;      // gy < h always by construction
        float r = 0.f, g = 0.f, b = 0.f;
        if (gx < w) {
            int idx = (gy * w + gx) * 3;
            r = xb[idx]; g = xb[idx + 1]; b = xb[idx + 2];
        }
        rr[k] = r; rg[k] = g; rb[k] = b;
        s_lum[ly + RAD][lx + RAD] = 0.2989f * r + 0.587f * g + 0.114f * b;
    }

    // ---- Phase 1b: halo ring lum -> LDS (zero outside image) ----
    for (int i = t; i < RH * RW; i += 256) {
        int ry = i / RW;
        int rx = i - ry * RW;
        if (ry >= RAD && ry < RAD + TH && rx >= RAD && rx < RAD + TW) continue;
        int gy = ty0 + ry - RAD, gx = tx0 + rx - RAD;
        float lum = 0.f;
        if (gy >= 0 && gy < h && gx >= 0 && gx < w) {
            int idx = (gy * w + gx) * 3;
            lum = 0.2989f * xb[idx] + 0.587f * xb[idx + 1] + 0.114f * xb[idx + 2];
        }
        s_lum[ry][rx] = lum;
    }
    __syncthreads();

    // ---- Phase 2: row conv (x-direction), 44x64 outputs ----
    for (int i = t; i < RH * TW; i += 256) {   // 2816 = 11*256 exact
        int r0 = i >> 6, c = i & 63;
        float sum = 0.f;
#pragma unroll
        for (int j = 0; j < 13; j++) sum += s_lum[r0][c + j] * G1[j];
        s_rc[r0][c] = sum;
    }
    __syncthreads();

    // ---- Phase 3: col conv + analytic dens + output ----
#pragma unroll
    for (int k = 0; k < 8; k++) {
        int p  = t + k * 256;
        int lx = p & 63, ly = p >> 6;
        int gy = ty0 + ly, gx = tx0 + lx;
        if (gx >= w) continue;
        float lum = 0.f;
#pragma unroll
        for (int j = 0; j < 13; j++) lum += s_rc[ly + j][lx] * G1[j];
        int ylo = min(RAD, gy), yhi = min(RAD, h - 1 - gy);
        int xlo = min(RAD, gx), xhi = min(RAD, w - 1 - gx);
        float Sy = PRE[RAD + yhi + 1] - PRE[RAD - ylo];
        float Sx = PRE[RAD + xhi + 1] - PRE[RAD - xlo];
        float dens  = WSUM * Sy * Sx;
        float scale = 1.0f / (lum / dens + EPSV);
        int idx = (gy * w + gx) * 3;
        ob[idx]     = rr[k] * scale;
        ob[idx + 1] = rg[k] * scale;
        ob[idx + 2] = rb[k] * scale;
    }
}

extern "C" void kernel_launch(void* const* d_in, const int* in_sizes, int n_in,
                              void* d_out, int out_size, void* d_ws, size_t ws_size,
                              hipStream_t stream) {
    const float* x = (const float*)d_in[0];
    float* out = (float*)d_out;
    mslln_kernel<<<5504, 256, 0, stream>>>(x, out);
}

// Round 3
// 244.892 us; speedup vs baseline: 1.1134x; 1.1134x over previous
//
#include <hip/hip_runtime.h>

// MultiscaleLLN: out = x / (gauss13x13(lum(x)) / dens + eps), 4 pyramid levels.
// Separable Gaussian; dens analytic via prefix sums. R3: fix 2-px row-conv
// offset (x-halo starts at tx0-8 for alignment, so tap base is c+2 not c).

#define NPIX   87040
#define EPSV   1e-3f
#define WSUM   0.9999f      // 0.2989 + 0.587 + 0.114
#define TW     64
#define TH     16
#define RAD    6
#define LW     80           // loaded px per row: [tx0-8, tx0+72)
#define LH     28           // loaded rows: [ty0-6, ty0+22)
#define NG     (LH * 20)    // 560 groups of 4 px

// 1D Gaussian taps G1[d+6] = exp(-d^2/18)/sqrt(18*pi), d = -6..6
__device__ __constant__ float G1[13] = {
    0.01799699f, 0.03315904f, 0.05467002f, 0.08065689f, 0.10648267f,
    0.12579441f, 0.13298076f, 0.12579441f, 0.10648267f, 0.08065689f,
    0.05467002f, 0.03315904f, 0.01799699f
};
// prefix sums PRE[i] = sum_{j<i} G1[j]
__device__ __constant__ float PRE[14] = {
    0.00000000f, 0.01799699f, 0.05115603f, 0.10582605f, 0.18648294f,
    0.29296561f, 0.41876002f, 0.55174078f, 0.67753519f, 0.78401786f,
    0.86467475f, 0.91934477f, 0.95250381f, 0.97050080f
};

__global__ __launch_bounds__(256)
void mslln_kernel(const float* __restrict__ x, float* __restrict__ out) {
    __shared__ float s_lum[LH][LW];     // 28x80 = 8.75 KB
    __shared__ float s_rc[LH][TW];      // 28x64 = 7 KB
    __shared__ float s_scale[TH][TW];   // 16x64 = 4 KB   (total 19.75 KB -> 8 blk/CU)

    const int bid = blockIdx.x;
    const int t   = threadIdx.x;

    // block -> (level, image, tile); tiles are 64x16 outputs
    // L0: 256x256 -> 4x16=64 tiles *128 = 8192   [0,8192)
    // L1: 128x128 -> 2x8 =16 tiles *128 = 2048   [8192,10240)
    // L2:  64x64  -> 1x4 =4  tiles *128 =  512   [10240,10752)
    // L3:  32x32  -> 1x2 =2  tiles *128 =  256   [10752,11008)
    int img, tl, txlog, h, off;
    if (bid < 8192)       { img = bid >> 6;                 tl = bid & 63; txlog = 2; h = 256; off = 0;     }
    else if (bid < 10240) { int r = bid - 8192;  img = r >> 4; tl = r & 15; txlog = 1; h = 128; off = 65536; }
    else if (bid < 10752) { int r = bid - 10240; img = r >> 2; tl = r & 3;  txlog = 0; h = 64;  off = 81920; }
    else                  { int r = bid - 10752; img = r >> 1; tl = r & 1;  txlog = 0; h = 32;  off = 86016; }
    const int w   = h;
    const int tx0 = (tl & ((1 << txlog) - 1)) << 6;  // *64
    const int ty0 = (tl >> txlog) << 4;              // *16

    const float* __restrict__ xb = x   + (size_t)img * (NPIX * 3) + (size_t)off * 3;
    float*       __restrict__ ob = out + (size_t)img * (NPIX * 3) + (size_t)off * 3;

    // ---- Phase 1: vectorized load, lum -> LDS (4 px / thread-iter) ----
#pragma unroll
    for (int k = 0; k < 3; k++) {
        unsigned i = t + k * 256;
        if (i < NG) {
            int gr  = i / 20;
            int gc  = i - gr * 20;
            int gy  = ty0 + gr - RAD;
            int gx0 = tx0 + (gc << 2) - 8;   // float index 3*gx0 is 16B-aligned
            float4 f0 = {0,0,0,0}, f1 = {0,0,0,0}, f2 = {0,0,0,0};
            if (gy >= 0 && gy < h) {
                if (gx0 >= 0 && gx0 + 3 < w) {
                    const float4* p = (const float4*)(xb + ((size_t)gy * w + gx0) * 3);
                    f0 = p[0]; f1 = p[1]; f2 = p[2];
                } else {
                    float v[12];
#pragma unroll
                    for (int c = 0; c < 12; c++) v[c] = 0.f;
#pragma unroll
                    for (int c = 0; c < 4; c++) {
                        int gx = gx0 + c;
                        if (gx >= 0 && gx < w) {
                            const float* s = xb + ((size_t)gy * w + gx) * 3;
                            v[3*c] = s[0]; v[3*c+1] = s[1]; v[3*c+2] = s[2];
                        }
                    }
                    f0 = make_float4(v[0], v[1], v[2],  v[3]);
                    f1 = make_float4(v[4], v[5], v[6],  v[7]);
                    f2 = make_float4(v[8], v[9], v[10], v[11]);
                }
            }
            float l0 = 0.2989f*f0.x + 0.587f*f0.y + 0.114f*f0.z;
            float l1 = 0.2989f*f0.w + 0.587f*f1.x + 0.114f*f1.y;
            float l2 = 0.2989f*f1.z + 0.587f*f1.w + 0.114f*f2.x;
            float l3 = 0.2989f*f2.y + 0.587f*f2.z + 0.114f*f2.w;
            *(float4*)&s_lum[gr][gc << 2] = make_float4(l0, l1, l2, l3);
        }
    }
    __syncthreads();

    // ---- Phase 2: row conv, 28x64 = 1792 = 7*256 exact ----
    // s_lum[r][c] holds pixel gx = tx0 + c - 8; output col c taps indices c+2..c+14
#pragma unroll
    for (int k = 0; k < 7; k++) {
        int i = t + k * 256;
        int r = i >> 6, c = i & 63;
        float s = 0.f;
#pragma unroll
        for (int j = 0; j < 13; j++) s += s_lum[r][c + 2 + j] * G1[j];
        s_rc[r][c] = s;
    }
    __syncthreads();

    // ---- Phase 3: col conv + analytic dens -> per-pixel scale ----
#pragma unroll
    for (int k = 0; k < 4; k++) {
        int i  = t + k * 256;
        int ly = i >> 6, lx = i & 63;
        if (tx0 + lx < w) {                 // only false on L3 (w=32)
            float s = 0.f;
#pragma unroll
            for (int j = 0; j < 13; j++) s += s_rc[ly + j][lx] * G1[j];
            int gy = ty0 + ly, gx = tx0 + lx;
            int ylo = min(RAD, gy), yhi = min(RAD, h - 1 - gy);
            int xlo = min(RAD, gx), xhi = min(RAD, w - 1 - gx);
            float Sy = PRE[RAD + yhi + 1] - PRE[RAD - ylo];
            float Sx = PRE[RAD + xhi + 1] - PRE[RAD - xlo];
            float dens = WSUM * Sy * Sx;
            s_scale[ly][lx] = 1.0f / (s / dens + EPSV);
        }
    }
    __syncthreads();

    // ---- Phase 4: re-read RGB (L1/L2 hit), scale, vectorized store ----
    {
        int gr  = t >> 4;            // 16 rows
        int gc  = t & 15;            // 16 groups of 4 px = 64 px
        int gx0 = tx0 + (gc << 2);
        if (gx0 < w) {               // only false on L3 (w=32)
            int gy = ty0 + gr;
            const float4* p = (const float4*)(xb + ((size_t)gy * w + gx0) * 3);
            float4 f0 = p[0], f1 = p[1], f2 = p[2];
            float4 sc = *(const float4*)&s_scale[gr][gc << 2];
            f0.x *= sc.x; f0.y *= sc.x; f0.z *= sc.x; f0.w *= sc.y;
            f1.x *= sc.y; f1.y *= sc.y; f1.z *= sc.z; f1.w *= sc.z;
            f2.x *= sc.z; f2.y *= sc.w; f2.z *= sc.w; f2.w *= sc.w;
            float4* q = (float4*)(ob + ((size_t)gy * w + gx0) * 3);
            q[0] = f0; q[1] = f1; q[2] = f2;
        }
    }
}

extern "C" void kernel_launch(void* const* d_in, const int* in_sizes, int n_in,
                              void* d_out, int out_size, void* d_ws, size_t ws_size,
                              hipStream_t stream) {
    const float* x = (const float*)d_in[0];
    float* out = (float*)d_out;
    mslln_kernel<<<11008, 256, 0, stream>>>(x, out);
}